// Round 17
// baseline (590.354 us; speedup 1.0000x reference)
//
#include <hip/hip_runtime.h>
#include <math.h>

#define H 128
#define I_DIM 128
#define T_STEPS 30
#define M_MODES 6
#define N_AG 8192
#define B_TOT (M_MODES * N_AG)   /* 49152 */
#define LN_EPS 1e-5f
#define MIN_SCALE 0.001f
#define LOG2E 1.44269504088896f

typedef short bf16x8 __attribute__((ext_vector_type(8)));
typedef float f32x4 __attribute__((ext_vector_type(4)));

#define MFMA16x16x32(A, B, C) __builtin_amdgcn_mfma_f32_16x16x32_bf16(A, B, C, 0, 0, 0)

__device__ __forceinline__ unsigned cvt_pk(float lo, float hi) {
    unsigned r;
    asm("v_cvt_pk_bf16_f32 %0, %1, %2" : "=v"(r) : "v"(lo), "v"(hi));
    return r;
}

__device__ __forceinline__ uint4 pack8(float4 a, float4 b) {
    uint4 r;
    r.x = cvt_pk(a.x, a.y); r.y = cvt_pk(a.z, a.w);
    r.z = cvt_pk(b.x, b.y); r.w = cvt_pk(b.z, b.w);
    return r;
}

__device__ __forceinline__ bf16x8 load8_cvt(const float* __restrict__ p) {
    return __builtin_bit_cast(bf16x8, pack8(((const float4*)p)[0], ((const float4*)p)[1]));
}

__device__ __forceinline__ bf16x8 load8_cvt_s(const float* __restrict__ p, float s) {
    float4 a = ((const float4*)p)[0];
    float4 b = ((const float4*)p)[1];
    a.x*=s; a.y*=s; a.z*=s; a.w*=s;
    b.x*=s; b.y*=s; b.z*=s; b.w*=s;
    return __builtin_bit_cast(bf16x8, pack8(a, b));
}

__device__ __forceinline__ short f2b(float f) {
    union { float f; unsigned u; } v; v.f = f;
    return (short)((v.u + 0x7FFFu + ((v.u >> 16) & 1u)) >> 16);
}

__device__ __forceinline__ float tanh2(float yp) {
    return 1.f - 2.f * __builtin_amdgcn_rcpf(1.f + __builtin_amdgcn_exp2f(yp));
}

__device__ __forceinline__ float elu1(float v) {
    return v > 0.f ? (v + (1.0f + MIN_SCALE))
                   : (__builtin_amdgcn_exp2f(v * LOG2E) + MIN_SCALE);
}

#define DPP_ADD(v, ctrl)                                                     \
    v += __builtin_bit_cast(float, __builtin_amdgcn_mov_dpp(                 \
             __builtin_bit_cast(int, v), ctrl, 0xF, 0xF, true))

__device__ __forceinline__ float red16(float v) {
    DPP_ADD(v, 0xB1);
    DPP_ADD(v, 0x4E);
    DPP_ADD(v, 0x124);
    DPP_ADD(v, 0x128);
    return v;
}

// ===========================================================================
// Single fused kernel: 256 blocks x 512 threads (8 waves), 1 block/CU.
//  Phase 1 (3 x 64-row tiles): GRU waves 0-3 + heads waves 4-7.
//    Heads run a ONE-INTERVAL LAG: compute from fragments loaded in the
//    previous interval (regs), then load this interval's h — LDS latency
//    comes off the critical path. Tail absorbed in the GRU-idle last
//    interval + post-loop.
//  Phase 2 (3 pi pairs).
// ===========================================================================
#define HB0 0
#define HB1 17408
#define GX23 34816
#define PI_INBF_OFF   0
#define PI_H1_OFF     33792
#define PI_REDL_OFF   51200
#define PI_RED3_OFF   53248
#define SM_BYTES      90112

__global__ __launch_bounds__(512, 1) void fused_kernel(
    const float* __restrict__ local_embed, const float* __restrict__ global_embed,
    const float* __restrict__ W_ih, const float* __restrict__ W_hh,
    const float* __restrict__ b_ih, const float* __restrict__ b_hh,
    int ntiles, int F,
    const float* __restrict__ loc1_w, const float* __restrict__ loc1_b,
    const float* __restrict__ loc_ln_g, const float* __restrict__ loc_ln_b,
    const float* __restrict__ loc2_w, const float* __restrict__ loc2_b,
    const float* __restrict__ sc1_w, const float* __restrict__ sc1_b,
    const float* __restrict__ sc_ln_g, const float* __restrict__ sc_ln_b,
    const float* __restrict__ sc2_w, const float* __restrict__ sc2_b,
    float* __restrict__ traj,
    const float* __restrict__ pi1_w, const float* __restrict__ pi1_b,
    const float* __restrict__ ln1_g, const float* __restrict__ ln1_b,
    const float* __restrict__ pi2_w, const float* __restrict__ pi2_b,
    const float* __restrict__ ln2_g, const float* __restrict__ ln2_b,
    const float* __restrict__ pi3_w, const float* __restrict__ pi3_b,
    float* __restrict__ pi_out)
{
    __shared__ __align__(16) char smraw[SM_BYTES];

    const int tid = threadIdx.x;
    const int w  = tid >> 6;          // wave 0..7
    const int l  = tid & 63;
    const int ln = l & 15;
    const int lg = l >> 4;

    // ======================= Phase 1: GRU + heads =======================
    if (w < 4) {
        // ================= GRU waves =================
        float bias_ih[3][2], bhn[2];
        #pragma unroll
        for (int u = 0; u < 2; ++u) {
            const int c = 32*w + 16*u + ln;
            bhn[u] = b_hh[2*H + c] * (2.f * LOG2E);
            #pragma unroll
            for (int g = 0; g < 3; ++g) {
                const float sc = (g < 2) ? LOG2E : (2.f * LOG2E);
                bias_ih[g][u] = (b_ih[g*H + c] + (g < 2 ? b_hh[g*H + c] : 0.f)) * sc;
            }
        }
        const int ro = ln*272 + lg*16;
        const int wb = (lg*4)*272 + (32*w + ln)*2;
        const int sr_ = tid >> 3;             // 0..31
        const int ssg = tid & 7;

        bf16x8 wf[3][2][4];
        f32x4 gxrz[2][2][2];
        f32x4 gxn[2][2];

        for (int it = blockIdx.x; it < ntiles; it += F) {
            const int lb0 = it * 64;
            __syncthreads();                           // B-top

            #pragma unroll
            for (int rr2 = 0; rr2 < 2; ++rr2) {
                const int r = sr_ + rr2*32;
                const int n = (lb0 + r) & (N_AG - 1);
                const float* src = local_embed + (size_t)n * H;
                #pragma unroll
                for (int hseg = 0; hseg < 2; ++hseg) {
                    const int s8 = ssg + hseg*8;
                    const float4 a = ((const float4*)(src + s8*8))[0];
                    const float4 c = ((const float4*)(src + s8*8))[1];
                    *(uint4*)(smraw + HB0 + r*272 + s8*16) = pack8(a, c);
                }
            }

            float h_reg[4][2][4];
            #pragma unroll
            for (int grp = 0; grp < 4; ++grp)
                #pragma unroll
                for (int u = 0; u < 2; ++u) {
                    const int j = 32*w + 16*u + ln;
                    #pragma unroll
                    for (int rg = 0; rg < 4; ++rg) {
                        const int n = (lb0 + grp*16 + lg*4 + rg) & (N_AG - 1);
                        h_reg[grp][u][rg] = local_embed[(size_t)n * H + j];
                    }
                }

            #pragma unroll
            for (int u = 0; u < 2; ++u)
                #pragma unroll
                for (int g = 0; g < 3; ++g) {
                    const int crow = g*H + 32*w + 16*u + ln;
                    const float sc = (g < 2) ? LOG2E : (2.f * LOG2E);
                    #pragma unroll
                    for (int kt = 0; kt < 4; ++kt)
                        wf[g][u][kt] = load8_cvt_s(W_ih + (size_t)crow * I_DIM + kt*32 + lg*8, sc);
                }
            __syncthreads();                           // B-stage

            #pragma unroll
            for (int grp = 0; grp < 4; ++grp) {
                bf16x8 ax[4];
                #pragma unroll
                for (int kt = 0; kt < 4; ++kt)
                    ax[kt] = *(const bf16x8*)(smraw + HB1 + ro + grp*4352 + kt*64);
                f32x4 ag[3][2];
                #pragma unroll
                for (int g = 0; g < 3; ++g)
                    #pragma unroll
                    for (int u = 0; u < 2; ++u) ag[g][u] = (f32x4)(0.f);
                __builtin_amdgcn_s_setprio(1);
                #pragma unroll
                for (int kt = 0; kt < 4; ++kt)
                    #pragma unroll
                    for (int g = 0; g < 3; ++g)
                        #pragma unroll
                        for (int u = 0; u < 2; ++u)
                            ag[g][u] = MFMA16x16x32(ax[kt], wf[g][u][kt], ag[g][u]);
                __builtin_amdgcn_s_setprio(0);
                #pragma unroll
                for (int g = 0; g < 3; ++g)
                    #pragma unroll
                    for (int u = 0; u < 2; ++u)
                        #pragma unroll
                        for (int rg = 0; rg < 4; ++rg)
                            ag[g][u][rg] += bias_ih[g][u];
                if (grp < 2) {
                    #pragma unroll
                    for (int u = 0; u < 2; ++u) {
                        gxrz[grp][0][u] = ag[0][u];
                        gxrz[grp][1][u] = ag[1][u];
                        gxn[grp][u]     = ag[2][u];
                    }
                } else {
                    const int r23 = (grp - 2)*16 + lg*4;
                    #pragma unroll
                    for (int g = 0; g < 3; ++g)
                        #pragma unroll
                        for (int u = 0; u < 2; ++u) {
                            const int ch = g*H + 32*w + 16*u + ln;
                            *(f32x4*)(smraw + GX23 + ((ch*36 + r23) << 2)) = ag[g][u];
                        }
                }
            }

            #pragma unroll
            for (int u = 0; u < 2; ++u)
                #pragma unroll
                for (int g = 0; g < 3; ++g) {
                    const int crow = g*H + 32*w + 16*u + ln;
                    const float sc = (g < 2) ? LOG2E : (2.f * LOG2E);
                    #pragma unroll
                    for (int kt = 0; kt < 4; ++kt)
                        wf[g][u][kt] = load8_cvt_s(W_hh + (size_t)crow * H + kt*32 + lg*8, sc);
                }
            __syncthreads();                           // B-gx

            int rd_off = HB0, wr_off = HB1;
            for (int i = 0; i <= T_STEPS; ++i) {
                if (i < T_STEPS) {
                    #pragma unroll
                    for (int grp = 0; grp < 4; ++grp) {
                        bf16x8 af[4];
                        #pragma unroll
                        for (int kt = 0; kt < 4; ++kt)
                            af[kt] = *(const bf16x8*)(smraw + rd_off + ro + grp*4352 + kt*64);

                        f32x4 ga[3][2];
                        f32x4 gxn_l[2];
                        if (grp < 2) {
                            #pragma unroll
                            for (int u = 0; u < 2; ++u) {
                                ga[0][u] = gxrz[grp][0][u];
                                ga[1][u] = gxrz[grp][1][u];
                                ga[2][u] = (f32x4)(0.f);
                                gxn_l[u] = gxn[grp][u];
                            }
                        } else {
                            const int r23 = (grp - 2)*16 + lg*4;
                            #pragma unroll
                            for (int u = 0; u < 2; ++u) {
                                const int ch = 32*w + 16*u + ln;
                                ga[0][u] = *(const f32x4*)(smraw + GX23 + ((ch*36 + r23) << 2));
                                ga[1][u] = *(const f32x4*)(smraw + GX23 + (((H + ch)*36 + r23) << 2));
                                ga[2][u] = (f32x4)(0.f);
                                gxn_l[u] = *(const f32x4*)(smraw + GX23 + (((2*H + ch)*36 + r23) << 2));
                            }
                        }

                        __builtin_amdgcn_s_setprio(1);
                        #pragma unroll
                        for (int kt = 0; kt < 4; ++kt)
                            #pragma unroll
                            for (int g = 0; g < 3; ++g)
                                #pragma unroll
                                for (int u = 0; u < 2; ++u)
                                    ga[g][u] = MFMA16x16x32(af[kt], wf[g][u][kt], ga[g][u]);
                        __builtin_amdgcn_s_setprio(0);

                        #pragma unroll
                        for (int u = 0; u < 2; ++u) {
                            float hv[4];
                            #pragma unroll
                            for (int rg = 0; rg < 4; ++rg) {
                                const float ea = __builtin_amdgcn_exp2f(-ga[0][u][rg]);
                                const float eb = __builtin_amdgcn_exp2f(-ga[1][u][rg]);
                                const float A  = 1.f + ea;
                                const float Bv_ = 1.f + eb;
                                const float R = __builtin_amdgcn_rcpf(A * Bv_);
                                const float rr = R * Bv_;
                                const float zz = R * A;
                                const float nn = tanh2(gxn_l[u][rg] + rr * (ga[2][u][rg] + bhn[u]));
                                const float h  = nn + zz * (h_reg[grp][u][rg] - nn);
                                h_reg[grp][u][rg] = h;
                                hv[rg] = h;
                            }
                            const unsigned p0 = cvt_pk(hv[0], hv[1]);
                            const unsigned p1 = cvt_pk(hv[2], hv[3]);
                            const int wa = wr_off + wb + grp*4352 + u*32;
                            *(short*)(smraw + wa)        = (short)p0;
                            *(short*)(smraw + wa + 272)  = (short)(p0 >> 16);
                            *(short*)(smraw + wa + 544)  = (short)p1;
                            *(short*)(smraw + wa + 816)  = (short)(p1 >> 16);
                        }
                    }
                }
                __syncthreads();                       // B-step
                rd_off ^= 17408; wr_off ^= 17408;
            }
        }
    } else {
        // ================= heads waves (one-interval lag) =================
        const int hw = w - 4;
        const int hd = hw & 1;
        const int mrow0 = (hw >> 1) * 16;

        const float* __restrict__ W1  = hd ? sc1_w   : loc1_w;
        const float* __restrict__ B1v = hd ? sc1_b   : loc1_b;
        const float* __restrict__ Gv  = hd ? sc_ln_g : loc_ln_g;
        const float* __restrict__ Bv  = hd ? sc_ln_b : loc_ln_b;
        const float* __restrict__ W2  = hd ? sc2_w   : loc2_w;
        const float* __restrict__ B2v = hd ? sc2_b   : loc2_b;

        bf16x8 whf[8][4];
        float bias1[8], lng[8], lnb[8], w2a[8], w2b[8];
        #pragma unroll
        for (int nt = 0; nt < 8; ++nt) {
            const int c = 16*nt + ln;
            #pragma unroll
            for (int kt = 0; kt < 4; ++kt)
                whf[nt][kt] = load8_cvt(W1 + (size_t)c * H + kt*32 + lg*8);
            bias1[nt] = B1v[c]; lng[nt] = Gv[c]; lnb[nt] = Bv[c];
            w2a[nt] = W2[c];    w2b[nt] = W2[H + c];
        }
        const float b2_0 = B2v[0], b2_1 = B2v[1];
        const int sr_ = (tid - 256) >> 3;
        const int ssg = tid & 7;

        for (int it = blockIdx.x; it < ntiles; it += F) {
            const int lb0 = it * 64;
            __syncthreads();                           // B-top

            #pragma unroll
            for (int rr2 = 0; rr2 < 2; ++rr2) {
                const int r = sr_ + rr2*32;
                const float* src = global_embed + (size_t)(lb0 + r) * I_DIM;
                #pragma unroll
                for (int hseg = 0; hseg < 2; ++hseg) {
                    const int s8 = ssg + hseg*8;
                    const float4 a = ((const float4*)(src + s8*8))[0];
                    const float4 c = ((const float4*)(src + s8*8))[1];
                    *(uint4*)(smraw + HB1 + r*272 + s8*16) = pack8(a, c);
                }
            }
            __syncthreads();                           // B-stage
            __syncthreads();                           // B-gx

            int rd_off = HB0;
            float2 pend[2][4];
            bf16x8 afp[2][4];

            for (int i = 0; i <= T_STEPS; ++i) {
                // store outputs computed two intervals back (t = i-3)
                if (i >= 3 && ln == 0) {
                    #pragma unroll
                    for (int rr = 0; rr < 2; ++rr)
                        #pragma unroll
                        for (int rg = 0; rg < 4; ++rg) {
                            const int b = lb0 + mrow0 + rr*32 + lg*4 + rg;
                            *(float2*)(traj + ((size_t)b * T_STEPS + (i - 3)) * 4 + hd*2) = pend[rr][rg];
                        }
                }
                // compute from lagged fragments afp = h(i-1) -> output t = i-2
                if (i >= 2) {
                    #pragma unroll
                    for (int rr = 0; rr < 2; ++rr) {
                        f32x4 acc[8];
                        #pragma unroll
                        for (int nt = 0; nt < 8; ++nt) acc[nt] = (f32x4)(0.f);
                        __builtin_amdgcn_s_setprio(1);
                        #pragma unroll
                        for (int kt = 0; kt < 4; ++kt)
                            #pragma unroll
                            for (int nt = 0; nt < 8; ++nt)
                                acc[nt] = MFMA16x16x32(afp[rr][kt], whf[nt][kt], acc[nt]);
                        __builtin_amdgcn_s_setprio(0);

                        #pragma unroll
                        for (int rg = 0; rg < 4; ++rg) {
                            float s = 0.f, q = 0.f;
                            #pragma unroll
                            for (int nt = 0; nt < 8; ++nt) {
                                const float a = acc[nt][rg] + bias1[nt];
                                acc[nt][rg] = a;
                                s += a; q += a*a;
                            }
                            s = red16(s);
                            q = red16(q);
                            const float mu = s * (1.f/H);
                            const float var = q * (1.f/H) - mu*mu;
                            const float rs = rsqrtf(var + LN_EPS);
                            const float murs = mu * rs;
                            float p0 = 0.f, p1 = 0.f;
                            #pragma unroll
                            for (int nt = 0; nt < 8; ++nt) {
                                float v = fmaf(fmaf(acc[nt][rg], rs, -murs), lng[nt], lnb[nt]);
                                v = fmaxf(v, 0.f);
                                p0 = fmaf(v, w2a[nt], p0);
                                p1 = fmaf(v, w2b[nt], p1);
                            }
                            p0 = red16(p0);
                            p1 = red16(p1);
                            float v0 = p0 + b2_0;
                            float v1 = p1 + b2_1;
                            if (hd) {
                                v0 = elu1(v0);
                                v1 = elu1(v1);
                            }
                            pend[rr][rg] = make_float2(v0, v1);
                        }
                    }
                }
                // load this interval's h(i) into afp (consumed next interval)
                if (i >= 1) {
                    #pragma unroll
                    for (int rr = 0; rr < 2; ++rr) {
                        const int ho = (mrow0 + rr*32 + ln)*272 + lg*16;
                        #pragma unroll
                        for (int kt = 0; kt < 4; ++kt)
                            afp[rr][kt] = *(const bf16x8*)(smraw + rd_off + ho + kt*64);
                    }
                }
                __syncthreads();                       // B-step
                rd_off ^= 17408;
            }

            // post-loop tail (no barriers; registers only):
            // pend holds t = T-2; afp holds h(T) -> output t = T-1
            if (ln == 0) {
                #pragma unroll
                for (int rr = 0; rr < 2; ++rr)
                    #pragma unroll
                    for (int rg = 0; rg < 4; ++rg) {
                        const int b = lb0 + mrow0 + rr*32 + lg*4 + rg;
                        *(float2*)(traj + ((size_t)b * T_STEPS + (T_STEPS - 2)) * 4 + hd*2) = pend[rr][rg];
                    }
            }
            #pragma unroll
            for (int rr = 0; rr < 2; ++rr) {
                f32x4 acc[8];
                #pragma unroll
                for (int nt = 0; nt < 8; ++nt) acc[nt] = (f32x4)(0.f);
                #pragma unroll
                for (int kt = 0; kt < 4; ++kt)
                    #pragma unroll
                    for (int nt = 0; nt < 8; ++nt)
                        acc[nt] = MFMA16x16x32(afp[rr][kt], whf[nt][kt], acc[nt]);

                #pragma unroll
                for (int rg = 0; rg < 4; ++rg) {
                    float s = 0.f, q = 0.f;
                    #pragma unroll
                    for (int nt = 0; nt < 8; ++nt) {
                        const float a = acc[nt][rg] + bias1[nt];
                        acc[nt][rg] = a;
                        s += a; q += a*a;
                    }
                    s = red16(s);
                    q = red16(q);
                    const float mu = s * (1.f/H);
                    const float var = q * (1.f/H) - mu*mu;
                    const float rs = rsqrtf(var + LN_EPS);
                    const float murs = mu * rs;
                    float p0 = 0.f, p1 = 0.f;
                    #pragma unroll
                    for (int nt = 0; nt < 8; ++nt) {
                        float v = fmaf(fmaf(acc[nt][rg], rs, -murs), lng[nt], lnb[nt]);
                        v = fmaxf(v, 0.f);
                        p0 = fmaf(v, w2a[nt], p0);
                        p1 = fmaf(v, w2b[nt], p1);
                    }
                    p0 = red16(p0);
                    p1 = red16(p1);
                    if (ln == 0) {
                        float v0 = p0 + b2_0;
                        float v1 = p1 + b2_1;
                        if (hd) {
                            v0 = elu1(v0);
                            v1 = elu1(v1);
                        }
                        const int b = lb0 + mrow0 + rr*32 + lg*4 + rg;
                        *(float2*)(traj + ((size_t)b * T_STEPS + (T_STEPS - 1)) * 4 + hd*2) = make_float2(v0, v1);
                    }
                }
            }
        }
    }

    // ======================= Phase 2: 3 pi pairs =======================
    {
        const int sub  = tid >> 8;
        const int stid = tid & 255;
        const int w4 = stid >> 6;

        short (*inbf)[264] = (short(*)[264])(smraw + PI_INBF_OFF + (size_t)sub*16896);
        short (*h1bf)[136] = (short(*)[136])(smraw + PI_H1_OFF   + (size_t)sub*8704);
        float (*redL)[32][2] = (float(*)[32][2])(smraw + PI_REDL_OFF + (size_t)sub*1024);
        float (*red3)[32]    = (float(*)[32])(smraw + PI_RED3_OFF + (size_t)sub*512);

        bf16x8 wf1[2][8];
        bf16x8 wf2[2][4];
        float b1[2], g1[2], bb1[2], b2[2], g2[2], bb2[2], w3[2];
        #pragma unroll
        for (int nt = 0; nt < 2; ++nt) {
            const int c = 32*w4 + 16*nt + ln;
            #pragma unroll
            for (int kt = 0; kt < 8; ++kt)
                wf1[nt][kt] = load8_cvt(pi1_w + (size_t)c * (2*H) + kt*32 + lg*8);
            #pragma unroll
            for (int kt = 0; kt < 4; ++kt)
                wf2[nt][kt] = load8_cvt(pi2_w + (size_t)c * H + kt*32 + lg*8);
            b1[nt] = pi1_b[c]; g1[nt] = ln1_g[c]; bb1[nt] = ln1_b[c];
            b2[nt] = pi2_b[c]; g2[nt] = ln2_g[c]; bb2[nt] = ln2_b[c];
            w3[nt] = pi3_w[c];
        }
        const float b3 = pi3_b[0];

        for (int p = 0; p < 3; ++p) {
            const int r0 = (((int)blockIdx.x*3 + p)*2 + sub) * 32;
            __syncthreads();
            {
                const int r   = stid >> 3;
                const int seg = stid & 7;
                const int b = r0 + r;
                const int n = b & (N_AG - 1);
                const float* src = (seg < 4) ? (local_embed + (size_t)n * H + seg * 32)
                                             : (global_embed + (size_t)b * I_DIM + (seg - 4) * 32);
                #pragma unroll
                for (int i = 0; i < 4; ++i) {
                    const float4 a = ((const float4*)src)[2*i];
                    const float4 c = ((const float4*)src)[2*i+1];
                    *(uint4*)&inbf[r][seg*32 + i*8] = pack8(a, c);
                }
            }
            __syncthreads();

            f32x4 acc1[2][2];
            #pragma unroll
            for (int m = 0; m < 2; ++m) {
                #pragma unroll
                for (int nt = 0; nt < 2; ++nt) acc1[m][nt] = (f32x4)(0.f);
                bf16x8 af[8];
                #pragma unroll
                for (int kt = 0; kt < 8; ++kt)
                    af[kt] = *(const bf16x8*)&inbf[m*16 + ln][kt*32 + lg*8];
                __builtin_amdgcn_s_setprio(1);
                #pragma unroll
                for (int kt = 0; kt < 8; ++kt)
                    #pragma unroll
                    for (int nt = 0; nt < 2; ++nt)
                        acc1[m][nt] = MFMA16x16x32(af[kt], wf1[nt][kt], acc1[m][nt]);
                __builtin_amdgcn_s_setprio(0);
            }

            #pragma unroll
            for (int m = 0; m < 2; ++m)
                #pragma unroll
                for (int rg = 0; rg < 4; ++rg) {
                    float s = 0.f, q = 0.f;
                    #pragma unroll
                    for (int nt = 0; nt < 2; ++nt) {
                        const float a = acc1[m][nt][rg] + b1[nt];
                        acc1[m][nt][rg] = a;
                        s += a; q += a*a;
                    }
                    s = red16(s);
                    q = red16(q);
                    if (ln == 0) {
                        const int row = m*16 + lg*4 + rg;
                        redL[w4][row][0] = s;
                        redL[w4][row][1] = q;
                    }
                }
            __syncthreads();

            #pragma unroll
            for (int m = 0; m < 2; ++m)
                #pragma unroll
                for (int rg = 0; rg < 4; ++rg) {
                    const int row = m*16 + lg*4 + rg;
                    const float S = redL[0][row][0] + redL[1][row][0] + redL[2][row][0] + redL[3][row][0];
                    const float Q = redL[0][row][1] + redL[1][row][1] + redL[2][row][1] + redL[3][row][1];
                    const float mu = S * (1.f/H);
                    const float var = Q * (1.f/H) - mu*mu;
                    const float rs = rsqrtf(var + LN_EPS);
                    #pragma unroll
                    for (int nt = 0; nt < 2; ++nt) {
                        const float v = fmaxf((acc1[m][nt][rg] - mu) * rs * g1[nt] + bb1[nt], 0.f);
                        h1bf[row][32*w4 + 16*nt + ln] = f2b(v);
                    }
                }
            __syncthreads();

            f32x4 acc2[2][2];
            #pragma unroll
            for (int m = 0; m < 2; ++m) {
                #pragma unroll
                for (int nt = 0; nt < 2; ++nt) acc2[m][nt] = (f32x4)(0.f);
                bf16x8 af[4];
                #pragma unroll
                for (int kt = 0; kt < 4; ++kt)
                    af[kt] = *(const bf16x8*)&h1bf[m*16 + ln][kt*32 + lg*8];
                __builtin_amdgcn_s_setprio(1);
                #pragma unroll
                for (int kt = 0; kt < 4; ++kt)
                    #pragma unroll
                    for (int nt = 0; nt < 2; ++nt)
                        acc2[m][nt] = MFMA16x16x32(af[kt], wf2[nt][kt], acc2[m][nt]);
                __builtin_amdgcn_s_setprio(0);
            }

            #pragma unroll
            for (int m = 0; m < 2; ++m)
                #pragma unroll
                for (int rg = 0; rg < 4; ++rg) {
                    float s = 0.f, q = 0.f;
                    #pragma unroll
                    for (int nt = 0; nt < 2; ++nt) {
                        const float a = acc2[m][nt][rg] + b2[nt];
                        acc2[m][nt][rg] = a;
                        s += a; q += a*a;
                    }
                    s = red16(s);
                    q = red16(q);
                    if (ln == 0) {
                        const int row = m*16 + lg*4 + rg;
                        redL[w4][row][0] = s;
                        redL[w4][row][1] = q;
                    }
                }
            __syncthreads();

            #pragma unroll
            for (int m = 0; m < 2; ++m)
                #pragma unroll
                for (int rg = 0; rg < 4; ++rg) {
                    const int row = m*16 + lg*4 + rg;
                    const float S = redL[0][row][0] + redL[1][row][0] + redL[2][row][0] + redL[3][row][0];
                    const float Q = redL[0][row][1] + redL[1][row][1] + redL[2][row][1] + redL[3][row][1];
                    const float mu = S * (1.f/H);
                    const float var = Q * (1.f/H) - mu*mu;
                    const float rs = rsqrtf(var + LN_EPS);
                    float p2 = 0.f;
                    #pragma unroll
                    for (int nt = 0; nt < 2; ++nt) {
                        const float v = fmaxf((acc2[m][nt][rg] - mu) * rs * g2[nt] + bb2[nt], 0.f);
                        p2 = fmaf(v, w3[nt], p2);
                    }
                    p2 = red16(p2);
                    if (ln == 0) red3[w4][row] = p2;
                }
            __syncthreads();

            if (stid < 32) {
                const int row = stid;
                const float pv = red3[0][row] + red3[1][row] + red3[2][row] + red3[3][row] + b3;
                const int b = r0 + row;
                const int n = b & (N_AG - 1);
                const int m = b >> 13;
                pi_out[(size_t)n * M_MODES + m] = pv;
            }
        }
    }
}

extern "C" void kernel_launch(void* const* d_in, const int* in_sizes, int n_in,
                              void* d_out, int out_size, void* d_ws, size_t ws_size,
                              hipStream_t stream) {
    (void)in_sizes; (void)n_in; (void)out_size; (void)d_ws; (void)ws_size;
    const float* local_embed  = (const float*)d_in[0];
    const float* global_embed = (const float*)d_in[1];
    const float* W_ih   = (const float*)d_in[2];
    const float* W_hh   = (const float*)d_in[3];
    const float* b_ih   = (const float*)d_in[4];
    const float* b_hh   = (const float*)d_in[5];
    const float* loc1_w = (const float*)d_in[6];
    const float* loc1_b = (const float*)d_in[7];
    const float* loc_ln_g = (const float*)d_in[8];
    const float* loc_ln_b = (const float*)d_in[9];
    const float* loc2_w = (const float*)d_in[10];
    const float* loc2_b = (const float*)d_in[11];
    const float* sc1_w  = (const float*)d_in[12];
    const float* sc1_b  = (const float*)d_in[13];
    const float* sc_ln_g = (const float*)d_in[14];
    const float* sc_ln_b = (const float*)d_in[15];
    const float* sc2_w  = (const float*)d_in[16];
    const float* sc2_b  = (const float*)d_in[17];
    const float* pi1_w  = (const float*)d_in[18];
    const float* pi1_b  = (const float*)d_in[19];
    const float* pi_ln1_g = (const float*)d_in[20];
    const float* pi_ln1_b = (const float*)d_in[21];
    const float* pi2_w  = (const float*)d_in[22];
    const float* pi2_b  = (const float*)d_in[23];
    const float* pi_ln2_g = (const float*)d_in[24];
    const float* pi_ln2_b = (const float*)d_in[25];
    const float* pi3_w  = (const float*)d_in[26];
    const float* pi3_b  = (const float*)d_in[27];

    float* traj = (float*)d_out;
    float* pi_out = traj + (size_t)B_TOT * T_STEPS * 4;

    const int ntiles = B_TOT / 64;   // 768 64-row tiles
    const int F = 256;               // 1 block/CU; 3 tiles + 3 pi pairs each

    fused_kernel<<<F, 512, 0, stream>>>(
        local_embed, global_embed, W_ih, W_hh, b_ih, b_hh,
        ntiles, F,
        loc1_w, loc1_b, loc_ln_g, loc_ln_b, loc2_w, loc2_b,
        sc1_w, sc1_b, sc_ln_g, sc_ln_b, sc2_w, sc2_b, traj,
        pi1_w, pi1_b, pi_ln1_g, pi_ln1_b,
        pi2_w, pi2_b, pi_ln2_g, pi_ln2_b, pi3_w, pi3_b, pi_out);
}

// Round 18
// 486.157 us; speedup vs baseline: 1.2143x; 1.2143x over previous
//
#include <hip/hip_runtime.h>
#include <math.h>

#define H 128
#define I_DIM 128
#define T_STEPS 30
#define M_MODES 6
#define N_AG 8192
#define B_TOT (M_MODES * N_AG)   /* 49152 */
#define LN_EPS 1e-5f
#define MIN_SCALE 0.001f
#define LOG2E 1.44269504088896f

typedef short bf16x8 __attribute__((ext_vector_type(8)));
typedef float f32x4 __attribute__((ext_vector_type(4)));

#define MFMA16x16x32(A, B, C) __builtin_amdgcn_mfma_f32_16x16x32_bf16(A, B, C, 0, 0, 0)

__device__ __forceinline__ unsigned cvt_pk(float lo, float hi) {
    unsigned r;
    asm("v_cvt_pk_bf16_f32 %0, %1, %2" : "=v"(r) : "v"(lo), "v"(hi));
    return r;
}

__device__ __forceinline__ uint4 pack8(float4 a, float4 b) {
    uint4 r;
    r.x = cvt_pk(a.x, a.y); r.y = cvt_pk(a.z, a.w);
    r.z = cvt_pk(b.x, b.y); r.w = cvt_pk(b.z, b.w);
    return r;
}

__device__ __forceinline__ bf16x8 load8_cvt(const float* __restrict__ p) {
    return __builtin_bit_cast(bf16x8, pack8(((const float4*)p)[0], ((const float4*)p)[1]));
}

__device__ __forceinline__ bf16x8 load8_cvt_s(const float* __restrict__ p, float s) {
    float4 a = ((const float4*)p)[0];
    float4 b = ((const float4*)p)[1];
    a.x*=s; a.y*=s; a.z*=s; a.w*=s;
    b.x*=s; b.y*=s; b.z*=s; b.w*=s;
    return __builtin_bit_cast(bf16x8, pack8(a, b));
}

__device__ __forceinline__ short f2b(float f) {
    union { float f; unsigned u; } v; v.f = f;
    return (short)((v.u + 0x7FFFu + ((v.u >> 16) & 1u)) >> 16);
}

__device__ __forceinline__ float tanh2(float yp) {
    return 1.f - 2.f * __builtin_amdgcn_rcpf(1.f + __builtin_amdgcn_exp2f(yp));
}

__device__ __forceinline__ float elu1(float v) {
    return v > 0.f ? (v + (1.0f + MIN_SCALE))
                   : (__builtin_amdgcn_exp2f(v * LOG2E) + MIN_SCALE);
}

#define DPP_ADD(v, ctrl)                                                     \
    v += __builtin_bit_cast(float, __builtin_amdgcn_mov_dpp(                 \
             __builtin_bit_cast(int, v), ctrl, 0xF, 0xF, true))

__device__ __forceinline__ float red16(float v) {
    DPP_ADD(v, 0xB1);
    DPP_ADD(v, 0x4E);
    DPP_ADD(v, 0x124);
    DPP_ADD(v, 0x128);
    return v;
}

// ===========================================================================
// Single fused kernel: 256 blocks x 512 threads (8 waves), 1 block/CU.
//  Phase 1 (3 x 64-row tiles): GRU waves 0-3 (each: 4 row-grps x 32 ch of all
//    3 gates) + heads waves 4-7 (each: one head x 2 row-grps).
//    gx for grps 0-1 folded into MFMA C-init (regs); grps 2-3 in LDS f32
//    (same-thread round trip, padded stride 36). n-gate gx kept separate.
//  Phase 2 (3 pi pairs): pi head, 2 x 256-thread groups.
// ===========================================================================
#define HB0 0
#define HB1 17408
#define GX23 34816            /* 384 ch x 36 f32 (rows 32..63) = 55296 B */
#define PI_INBF_OFF   0
#define PI_H1_OFF     33792
#define PI_REDL_OFF   51200
#define PI_RED3_OFF   53248
#define SM_BYTES      90112

__global__ __launch_bounds__(512, 1) void fused_kernel(
    const float* __restrict__ local_embed, const float* __restrict__ global_embed,
    const float* __restrict__ W_ih, const float* __restrict__ W_hh,
    const float* __restrict__ b_ih, const float* __restrict__ b_hh,
    int ntiles, int F,
    const float* __restrict__ loc1_w, const float* __restrict__ loc1_b,
    const float* __restrict__ loc_ln_g, const float* __restrict__ loc_ln_b,
    const float* __restrict__ loc2_w, const float* __restrict__ loc2_b,
    const float* __restrict__ sc1_w, const float* __restrict__ sc1_b,
    const float* __restrict__ sc_ln_g, const float* __restrict__ sc_ln_b,
    const float* __restrict__ sc2_w, const float* __restrict__ sc2_b,
    float* __restrict__ traj,
    const float* __restrict__ pi1_w, const float* __restrict__ pi1_b,
    const float* __restrict__ ln1_g, const float* __restrict__ ln1_b,
    const float* __restrict__ pi2_w, const float* __restrict__ pi2_b,
    const float* __restrict__ ln2_g, const float* __restrict__ ln2_b,
    const float* __restrict__ pi3_w, const float* __restrict__ pi3_b,
    float* __restrict__ pi_out)
{
    __shared__ __align__(16) char smraw[SM_BYTES];

    const int tid = threadIdx.x;
    const int w  = tid >> 6;          // wave 0..7
    const int l  = tid & 63;
    const int ln = l & 15;
    const int lg = l >> 4;

    // ======================= Phase 1: GRU + heads =======================
    if (w < 4) {
        // ================= GRU waves =================
        float bias_ih[3][2], bhn[2];
        #pragma unroll
        for (int u = 0; u < 2; ++u) {
            const int c = 32*w + 16*u + ln;
            bhn[u] = b_hh[2*H + c] * (2.f * LOG2E);
            #pragma unroll
            for (int g = 0; g < 3; ++g) {
                const float sc = (g < 2) ? LOG2E : (2.f * LOG2E);
                bias_ih[g][u] = (b_ih[g*H + c] + (g < 2 ? b_hh[g*H + c] : 0.f)) * sc;
            }
        }
        const int ro = ln*272 + lg*16;
        const int wb = (lg*4)*272 + (32*w + ln)*2;
        const int sr_ = tid >> 3;             // 0..31
        const int ssg = tid & 7;

        bf16x8 wf[3][2][4];
        f32x4 gxrz[2][2][2];                  // [grp<2][g(0,1)][u]
        f32x4 gxn[2][2];                      // [grp<2][u]

        for (int it = blockIdx.x; it < ntiles; it += F) {
            const int lb0 = it * 64;
            __syncthreads();                           // B-top

            // stage h0 -> hb0 (64 rows)
            #pragma unroll
            for (int rr2 = 0; rr2 < 2; ++rr2) {
                const int r = sr_ + rr2*32;
                const int n = (lb0 + r) & (N_AG - 1);
                const float* src = local_embed + (size_t)n * H;
                #pragma unroll
                for (int hseg = 0; hseg < 2; ++hseg) {
                    const int s8 = ssg + hseg*8;
                    const float4 a = ((const float4*)(src + s8*8))[0];
                    const float4 c = ((const float4*)(src + s8*8))[1];
                    *(uint4*)(smraw + HB0 + r*272 + s8*16) = pack8(a, c);
                }
            }

            float h_reg[4][2][4];
            #pragma unroll
            for (int grp = 0; grp < 4; ++grp)
                #pragma unroll
                for (int u = 0; u < 2; ++u) {
                    const int j = 32*w + 16*u + ln;
                    #pragma unroll
                    for (int rg = 0; rg < 4; ++rg) {
                        const int n = (lb0 + grp*16 + lg*4 + rg) & (N_AG - 1);
                        h_reg[grp][u][rg] = local_embed[(size_t)n * H + j];
                    }
                }

            // W_ih fragments (scaled) into wf
            #pragma unroll
            for (int u = 0; u < 2; ++u)
                #pragma unroll
                for (int g = 0; g < 3; ++g) {
                    const int crow = g*H + 32*w + 16*u + ln;
                    const float sc = (g < 2) ? LOG2E : (2.f * LOG2E);
                    #pragma unroll
                    for (int kt = 0; kt < 4; ++kt)
                        wf[g][u][kt] = load8_cvt_s(W_ih + (size_t)crow * I_DIM + kt*32 + lg*8, sc);
                }
            __syncthreads();                           // B-stage (x,h0 staged)

            // gx = x @ W_ih^T (+bias); grps 0-1 -> regs, grps 2-3 -> LDS f32
            #pragma unroll
            for (int grp = 0; grp < 4; ++grp) {
                bf16x8 ax[4];
                #pragma unroll
                for (int kt = 0; kt < 4; ++kt)
                    ax[kt] = *(const bf16x8*)(smraw + HB1 + ro + grp*4352 + kt*64);
                f32x4 ag[3][2];
                #pragma unroll
                for (int g = 0; g < 3; ++g)
                    #pragma unroll
                    for (int u = 0; u < 2; ++u) ag[g][u] = (f32x4)(0.f);
                __builtin_amdgcn_s_setprio(1);
                #pragma unroll
                for (int kt = 0; kt < 4; ++kt)
                    #pragma unroll
                    for (int g = 0; g < 3; ++g)
                        #pragma unroll
                        for (int u = 0; u < 2; ++u)
                            ag[g][u] = MFMA16x16x32(ax[kt], wf[g][u][kt], ag[g][u]);
                __builtin_amdgcn_s_setprio(0);
                #pragma unroll
                for (int g = 0; g < 3; ++g)
                    #pragma unroll
                    for (int u = 0; u < 2; ++u)
                        #pragma unroll
                        for (int rg = 0; rg < 4; ++rg)
                            ag[g][u][rg] += bias_ih[g][u];
                if (grp < 2) {
                    #pragma unroll
                    for (int u = 0; u < 2; ++u) {
                        gxrz[grp][0][u] = ag[0][u];
                        gxrz[grp][1][u] = ag[1][u];
                        gxn[grp][u]     = ag[2][u];
                    }
                } else {
                    const int r23 = (grp - 2)*16 + lg*4;
                    #pragma unroll
                    for (int g = 0; g < 3; ++g)
                        #pragma unroll
                        for (int u = 0; u < 2; ++u) {
                            const int ch = g*H + 32*w + 16*u + ln;
                            *(f32x4*)(smraw + GX23 + ((ch*36 + r23) << 2)) = ag[g][u];
                        }
                }
            }

            // overwrite wf with W_hh fragments (scaled)
            #pragma unroll
            for (int u = 0; u < 2; ++u)
                #pragma unroll
                for (int g = 0; g < 3; ++g) {
                    const int crow = g*H + 32*w + 16*u + ln;
                    const float sc = (g < 2) ? LOG2E : (2.f * LOG2E);
                    #pragma unroll
                    for (int kt = 0; kt < 4; ++kt)
                        wf[g][u][kt] = load8_cvt_s(W_hh + (size_t)crow * H + kt*32 + lg*8, sc);
                }
            __syncthreads();                           // B-gx (hb1 free now)

            int rd_off = HB0, wr_off = HB1;
            for (int i = 0; i <= T_STEPS; ++i) {
                if (i < T_STEPS) {
                    #pragma unroll
                    for (int grp = 0; grp < 4; ++grp) {
                        bf16x8 af[4];
                        #pragma unroll
                        for (int kt = 0; kt < 4; ++kt)
                            af[kt] = *(const bf16x8*)(smraw + rd_off + ro + grp*4352 + kt*64);

                        // accumulator init: r/z gates start at gx (fold);
                        // n gate starts at 0, its gx kept separate.
                        f32x4 ga[3][2];
                        f32x4 gxn_l[2];
                        if (grp < 2) {
                            #pragma unroll
                            for (int u = 0; u < 2; ++u) {
                                ga[0][u] = gxrz[grp][0][u];
                                ga[1][u] = gxrz[grp][1][u];
                                ga[2][u] = (f32x4)(0.f);
                                gxn_l[u] = gxn[grp][u];
                            }
                        } else {
                            const int r23 = (grp - 2)*16 + lg*4;
                            #pragma unroll
                            for (int u = 0; u < 2; ++u) {
                                const int ch = 32*w + 16*u + ln;
                                ga[0][u] = *(const f32x4*)(smraw + GX23 + ((ch*36 + r23) << 2));
                                ga[1][u] = *(const f32x4*)(smraw + GX23 + (((H + ch)*36 + r23) << 2));
                                ga[2][u] = (f32x4)(0.f);
                                gxn_l[u] = *(const f32x4*)(smraw + GX23 + (((2*H + ch)*36 + r23) << 2));
                            }
                        }

                        __builtin_amdgcn_s_setprio(1);
                        #pragma unroll
                        for (int kt = 0; kt < 4; ++kt)
                            #pragma unroll
                            for (int g = 0; g < 3; ++g)
                                #pragma unroll
                                for (int u = 0; u < 2; ++u)
                                    ga[g][u] = MFMA16x16x32(af[kt], wf[g][u][kt], ga[g][u]);
                        __builtin_amdgcn_s_setprio(0);

                        #pragma unroll
                        for (int u = 0; u < 2; ++u) {
                            float hv[4];
                            #pragma unroll
                            for (int rg = 0; rg < 4; ++rg) {
                                const float ea = __builtin_amdgcn_exp2f(-ga[0][u][rg]);
                                const float eb = __builtin_amdgcn_exp2f(-ga[1][u][rg]);
                                const float A  = 1.f + ea;
                                const float Bv_ = 1.f + eb;
                                const float R = __builtin_amdgcn_rcpf(A * Bv_);
                                const float rr = R * Bv_;
                                const float zz = R * A;
                                const float nn = tanh2(gxn_l[u][rg] + rr * (ga[2][u][rg] + bhn[u]));
                                const float h  = nn + zz * (h_reg[grp][u][rg] - nn);
                                h_reg[grp][u][rg] = h;
                                hv[rg] = h;
                            }
                            const unsigned p0 = cvt_pk(hv[0], hv[1]);
                            const unsigned p1 = cvt_pk(hv[2], hv[3]);
                            const int wa = wr_off + wb + grp*4352 + u*32;
                            *(short*)(smraw + wa)        = (short)p0;
                            *(short*)(smraw + wa + 272)  = (short)(p0 >> 16);
                            *(short*)(smraw + wa + 544)  = (short)p1;
                            *(short*)(smraw + wa + 816)  = (short)(p1 >> 16);
                        }
                    }
                }
                __syncthreads();                       // B-step
                rd_off ^= 17408; wr_off ^= 17408;
            }
        }
    } else {
        // ================= heads waves: one head x 2 row-groups =================
        const int hw = w - 4;
        const int hd = hw & 1;
        const int mrow0 = (hw >> 1) * 16;      // row-groups: mrow0, mrow0+32

        const float* __restrict__ W1  = hd ? sc1_w   : loc1_w;
        const float* __restrict__ B1v = hd ? sc1_b   : loc1_b;
        const float* __restrict__ Gv  = hd ? sc_ln_g : loc_ln_g;
        const float* __restrict__ Bv  = hd ? sc_ln_b : loc_ln_b;
        const float* __restrict__ W2  = hd ? sc2_w   : loc2_w;
        const float* __restrict__ B2v = hd ? sc2_b   : loc2_b;

        bf16x8 whf[8][4];
        float bias1[8], lng[8], lnb[8], w2a[8], w2b[8];
        #pragma unroll
        for (int nt = 0; nt < 8; ++nt) {
            const int c = 16*nt + ln;
            #pragma unroll
            for (int kt = 0; kt < 4; ++kt)
                whf[nt][kt] = load8_cvt(W1 + (size_t)c * H + kt*32 + lg*8);
            bias1[nt] = B1v[c]; lng[nt] = Gv[c]; lnb[nt] = Bv[c];
            w2a[nt] = W2[c];    w2b[nt] = W2[H + c];
        }
        const float b2_0 = B2v[0], b2_1 = B2v[1];
        const int sr_ = (tid - 256) >> 3;      // 0..31
        const int ssg = tid & 7;

        for (int it = blockIdx.x; it < ntiles; it += F) {
            const int lb0 = it * 64;
            __syncthreads();                           // B-top

            // stage x -> hb1 (64 rows)
            #pragma unroll
            for (int rr2 = 0; rr2 < 2; ++rr2) {
                const int r = sr_ + rr2*32;
                const float* src = global_embed + (size_t)(lb0 + r) * I_DIM;
                #pragma unroll
                for (int hseg = 0; hseg < 2; ++hseg) {
                    const int s8 = ssg + hseg*8;
                    const float4 a = ((const float4*)(src + s8*8))[0];
                    const float4 c = ((const float4*)(src + s8*8))[1];
                    *(uint4*)(smraw + HB1 + r*272 + s8*16) = pack8(a, c);
                }
            }
            __syncthreads();                           // B-stage
            __syncthreads();                           // B-gx

            int rd_off = HB0;
            float2 pend[2][4];
            for (int i = 0; i <= T_STEPS; ++i) {
                if (i >= 2 && ln == 0) {
                    #pragma unroll
                    for (int rr = 0; rr < 2; ++rr)
                        #pragma unroll
                        for (int rg = 0; rg < 4; ++rg) {
                            const int b = lb0 + mrow0 + rr*32 + lg*4 + rg;
                            *(float2*)(traj + ((size_t)b * T_STEPS + (i - 2)) * 4 + hd*2) = pend[rr][rg];
                        }
                }
                if (i >= 1) {
                    #pragma unroll
                    for (int rr = 0; rr < 2; ++rr) {
                        const int ho = (mrow0 + rr*32 + ln)*272 + lg*16;
                        bf16x8 af[4];
                        #pragma unroll
                        for (int kt = 0; kt < 4; ++kt)
                            af[kt] = *(const bf16x8*)(smraw + rd_off + ho + kt*64);

                        f32x4 acc[8];
                        #pragma unroll
                        for (int nt = 0; nt < 8; ++nt) acc[nt] = (f32x4)(0.f);
                        __builtin_amdgcn_s_setprio(1);
                        #pragma unroll
                        for (int kt = 0; kt < 4; ++kt)
                            #pragma unroll
                            for (int nt = 0; nt < 8; ++nt)
                                acc[nt] = MFMA16x16x32(af[kt], whf[nt][kt], acc[nt]);
                        __builtin_amdgcn_s_setprio(0);

                        #pragma unroll
                        for (int rg = 0; rg < 4; ++rg) {
                            float s = 0.f, q = 0.f;
                            #pragma unroll
                            for (int nt = 0; nt < 8; ++nt) {
                                const float a = acc[nt][rg] + bias1[nt];
                                acc[nt][rg] = a;
                                s += a; q += a*a;
                            }
                            s = red16(s);
                            q = red16(q);
                            const float mu = s * (1.f/H);
                            const float var = q * (1.f/H) - mu*mu;
                            const float rs = rsqrtf(var + LN_EPS);
                            const float murs = mu * rs;
                            float p0 = 0.f, p1 = 0.f;
                            #pragma unroll
                            for (int nt = 0; nt < 8; ++nt) {
                                float v = fmaf(fmaf(acc[nt][rg], rs, -murs), lng[nt], lnb[nt]);
                                v = fmaxf(v, 0.f);
                                p0 = fmaf(v, w2a[nt], p0);
                                p1 = fmaf(v, w2b[nt], p1);
                            }
                            p0 = red16(p0);
                            p1 = red16(p1);
                            float v0 = p0 + b2_0;
                            float v1 = p1 + b2_1;
                            if (hd) {
                                v0 = elu1(v0);
                                v1 = elu1(v1);
                            }
                            pend[rr][rg] = make_float2(v0, v1);
                        }
                    }
                }
                __syncthreads();                       // B-step
                rd_off ^= 17408;
            }
            if (ln == 0) {
                #pragma unroll
                for (int rr = 0; rr < 2; ++rr)
                    #pragma unroll
                    for (int rg = 0; rg < 4; ++rg) {
                        const int b = lb0 + mrow0 + rr*32 + lg*4 + rg;
                        *(float2*)(traj + ((size_t)b * T_STEPS + (T_STEPS - 1)) * 4 + hd*2) = pend[rr][rg];
                    }
            }
        }
    }

    // ======================= Phase 2: 3 pi pairs =======================
    {
        const int sub  = tid >> 8;
        const int stid = tid & 255;
        const int w4 = stid >> 6;

        short (*inbf)[264] = (short(*)[264])(smraw + PI_INBF_OFF + (size_t)sub*16896);
        short (*h1bf)[136] = (short(*)[136])(smraw + PI_H1_OFF   + (size_t)sub*8704);
        float (*redL)[32][2] = (float(*)[32][2])(smraw + PI_REDL_OFF + (size_t)sub*1024);
        float (*red3)[32]    = (float(*)[32])(smraw + PI_RED3_OFF + (size_t)sub*512);

        bf16x8 wf1[2][8];
        bf16x8 wf2[2][4];
        float b1[2], g1[2], bb1[2], b2[2], g2[2], bb2[2], w3[2];
        #pragma unroll
        for (int nt = 0; nt < 2; ++nt) {
            const int c = 32*w4 + 16*nt + ln;
            #pragma unroll
            for (int kt = 0; kt < 8; ++kt)
                wf1[nt][kt] = load8_cvt(pi1_w + (size_t)c * (2*H) + kt*32 + lg*8);
            #pragma unroll
            for (int kt = 0; kt < 4; ++kt)
                wf2[nt][kt] = load8_cvt(pi2_w + (size_t)c * H + kt*32 + lg*8);
            b1[nt] = pi1_b[c]; g1[nt] = ln1_g[c]; bb1[nt] = ln1_b[c];
            b2[nt] = pi2_b[c]; g2[nt] = ln2_g[c]; bb2[nt] = ln2_b[c];
            w3[nt] = pi3_w[c];
        }
        const float b3 = pi3_b[0];

        for (int p = 0; p < 3; ++p) {
            const int r0 = (((int)blockIdx.x*3 + p)*2 + sub) * 32;
            __syncthreads();       // prior LDS uses retired
            {
                const int r   = stid >> 3;
                const int seg = stid & 7;
                const int b = r0 + r;
                const int n = b & (N_AG - 1);
                const float* src = (seg < 4) ? (local_embed + (size_t)n * H + seg * 32)
                                             : (global_embed + (size_t)b * I_DIM + (seg - 4) * 32);
                #pragma unroll
                for (int i = 0; i < 4; ++i) {
                    const float4 a = ((const float4*)src)[2*i];
                    const float4 c = ((const float4*)src)[2*i+1];
                    *(uint4*)&inbf[r][seg*32 + i*8] = pack8(a, c);
                }
            }
            __syncthreads();

            f32x4 acc1[2][2];
            #pragma unroll
            for (int m = 0; m < 2; ++m) {
                #pragma unroll
                for (int nt = 0; nt < 2; ++nt) acc1[m][nt] = (f32x4)(0.f);
                bf16x8 af[8];
                #pragma unroll
                for (int kt = 0; kt < 8; ++kt)
                    af[kt] = *(const bf16x8*)&inbf[m*16 + ln][kt*32 + lg*8];
                __builtin_amdgcn_s_setprio(1);
                #pragma unroll
                for (int kt = 0; kt < 8; ++kt)
                    #pragma unroll
                    for (int nt = 0; nt < 2; ++nt)
                        acc1[m][nt] = MFMA16x16x32(af[kt], wf1[nt][kt], acc1[m][nt]);
                __builtin_amdgcn_s_setprio(0);
            }

            #pragma unroll
            for (int m = 0; m < 2; ++m)
                #pragma unroll
                for (int rg = 0; rg < 4; ++rg) {
                    float s = 0.f, q = 0.f;
                    #pragma unroll
                    for (int nt = 0; nt < 2; ++nt) {
                        const float a = acc1[m][nt][rg] + b1[nt];
                        acc1[m][nt][rg] = a;
                        s += a; q += a*a;
                    }
                    s = red16(s);
                    q = red16(q);
                    if (ln == 0) {
                        const int row = m*16 + lg*4 + rg;
                        redL[w4][row][0] = s;
                        redL[w4][row][1] = q;
                    }
                }
            __syncthreads();

            #pragma unroll
            for (int m = 0; m < 2; ++m)
                #pragma unroll
                for (int rg = 0; rg < 4; ++rg) {
                    const int row = m*16 + lg*4 + rg;
                    const float S = redL[0][row][0] + redL[1][row][0] + redL[2][row][0] + redL[3][row][0];
                    const float Q = redL[0][row][1] + redL[1][row][1] + redL[2][row][1] + redL[3][row][1];
                    const float mu = S * (1.f/H);
                    const float var = Q * (1.f/H) - mu*mu;
                    const float rs = rsqrtf(var + LN_EPS);
                    #pragma unroll
                    for (int nt = 0; nt < 2; ++nt) {
                        const float v = fmaxf((acc1[m][nt][rg] - mu) * rs * g1[nt] + bb1[nt], 0.f);
                        h1bf[row][32*w4 + 16*nt + ln] = f2b(v);
                    }
                }
            __syncthreads();

            f32x4 acc2[2][2];
            #pragma unroll
            for (int m = 0; m < 2; ++m) {
                #pragma unroll
                for (int nt = 0; nt < 2; ++nt) acc2[m][nt] = (f32x4)(0.f);
                bf16x8 af[4];
                #pragma unroll
                for (int kt = 0; kt < 4; ++kt)
                    af[kt] = *(const bf16x8*)&h1bf[m*16 + ln][kt*32 + lg*8];
                __builtin_amdgcn_s_setprio(1);
                #pragma unroll
                for (int kt = 0; kt < 4; ++kt)
                    #pragma unroll
                    for (int nt = 0; nt < 2; ++nt)
                        acc2[m][nt] = MFMA16x16x32(af[kt], wf2[nt][kt], acc2[m][nt]);
                __builtin_amdgcn_s_setprio(0);
            }

            #pragma unroll
            for (int m = 0; m < 2; ++m)
                #pragma unroll
                for (int rg = 0; rg < 4; ++rg) {
                    float s = 0.f, q = 0.f;
                    #pragma unroll
                    for (int nt = 0; nt < 2; ++nt) {
                        const float a = acc2[m][nt][rg] + b2[nt];
                        acc2[m][nt][rg] = a;
                        s += a; q += a*a;
                    }
                    s = red16(s);
                    q = red16(q);
                    if (ln == 0) {
                        const int row = m*16 + lg*4 + rg;
                        redL[w4][row][0] = s;
                        redL[w4][row][1] = q;
                    }
                }
            __syncthreads();

            #pragma unroll
            for (int m = 0; m < 2; ++m)
                #pragma unroll
                for (int rg = 0; rg < 4; ++rg) {
                    const int row = m*16 + lg*4 + rg;
                    const float S = redL[0][row][0] + redL[1][row][0] + redL[2][row][0] + redL[3][row][0];
                    const float Q = redL[0][row][1] + redL[1][row][1] + redL[2][row][1] + redL[3][row][1];
                    const float mu = S * (1.f/H);
                    const float var = Q * (1.f/H) - mu*mu;
                    const float rs = rsqrtf(var + LN_EPS);
                    float p2 = 0.f;
                    #pragma unroll
                    for (int nt = 0; nt < 2; ++nt) {
                        const float v = fmaxf((acc2[m][nt][rg] - mu) * rs * g2[nt] + bb2[nt], 0.f);
                        p2 = fmaf(v, w3[nt], p2);
                    }
                    p2 = red16(p2);
                    if (ln == 0) red3[w4][row] = p2;
                }
            __syncthreads();

            if (stid < 32) {
                const int row = stid;
                const float pv = red3[0][row] + red3[1][row] + red3[2][row] + red3[3][row] + b3;
                const int b = r0 + row;
                const int n = b & (N_AG - 1);
                const int m = b >> 13;
                pi_out[(size_t)n * M_MODES + m] = pv;
            }
        }
    }
}

extern "C" void kernel_launch(void* const* d_in, const int* in_sizes, int n_in,
                              void* d_out, int out_size, void* d_ws, size_t ws_size,
                              hipStream_t stream) {
    (void)in_sizes; (void)n_in; (void)out_size; (void)d_ws; (void)ws_size;
    const float* local_embed  = (const float*)d_in[0];
    const float* global_embed = (const float*)d_in[1];
    const float* W_ih   = (const float*)d_in[2];
    const float* W_hh   = (const float*)d_in[3];
    const float* b_ih   = (const float*)d_in[4];
    const float* b_hh   = (const float*)d_in[5];
    const float* loc1_w = (const float*)d_in[6];
    const float* loc1_b = (const float*)d_in[7];
    const float* loc_ln_g = (const float*)d_in[8];
    const float* loc_ln_b = (const float*)d_in[9];
    const float* loc2_w = (const float*)d_in[10];
    const float* loc2_b = (const float*)d_in[11];
    const float* sc1_w  = (const float*)d_in[12];
    const float* sc1_b  = (const float*)d_in[13];
    const float* sc_ln_g = (const float*)d_in[14];
    const float* sc_ln_b = (const float*)d_in[15];
    const float* sc2_w  = (const float*)d_in[16];
    const float* sc2_b  = (const float*)d_in[17];
    const float* pi1_w  = (const float*)d_in[18];
    const float* pi1_b  = (const float*)d_in[19];
    const float* pi_ln1_g = (const float*)d_in[20];
    const float* pi_ln1_b = (const float*)d_in[21];
    const float* pi2_w  = (const float*)d_in[22];
    const float* pi2_b  = (const float*)d_in[23];
    const float* pi_ln2_g = (const float*)d_in[24];
    const float* pi_ln2_b = (const float*)d_in[25];
    const float* pi3_w  = (const float*)d_in[26];
    const float* pi3_b  = (const float*)d_in[27];

    float* traj = (float*)d_out;
    float* pi_out = traj + (size_t)B_TOT * T_STEPS * 4;

    const int ntiles = B_TOT / 64;   // 768 64-row tiles
    const int F = 256;               // 1 block/CU; 3 tiles + 3 pi pairs each

    fused_kernel<<<F, 512, 0, stream>>>(
        local_embed, global_embed, W_ih, W_hh, b_ih, b_hh,
        ntiles, F,
        loc1_w, loc1_b, loc_ln_g, loc_ln_b, loc2_w, loc2_b,
        sc1_w, sc1_b, sc_ln_g, sc_ln_b, sc2_w, sc2_b, traj,
        pi1_w, pi1_b, pi_ln1_g, pi_ln1_b,
        pi2_w, pi2_b, pi_ln2_g, pi_ln2_b, pi3_w, pi3_b, pi_out);
}